// Round 6
// baseline (338.212 us; speedup 1.0000x reference)
//
#include <hip/hip_runtime.h>
#include <hip/hip_bf16.h>

#define BIG 1e30f

typedef __attribute__((ext_vector_type(8))) short short8;
typedef __attribute__((ext_vector_type(4))) float f32x4;

__device__ __forceinline__ unsigned pk_bf16(float lo, float hi) {
    unsigned r;
    asm("v_cvt_pk_bf16_f32 %0, %1, %2" : "=v"(r) : "v"(lo), "v"(hi));
    return r;
}

// 8 consecutive-k f32 values -> one bf16x8 MFMA fragment (k-major)
__device__ __forceinline__ short8 make_frag(float4 a, float4 c) {
    union { unsigned u[4]; short8 s; } cv;
    cv.u[0] = pk_bf16(a.x, a.y);
    cv.u[1] = pk_bf16(a.z, a.w);
    cv.u[2] = pk_bf16(c.x, c.y);
    cv.u[3] = pk_bf16(c.z, c.w);
    return cv.s;
}

// Fused pairwise-sqeuclidean (bf16 MFMA) + DTW, one block per batch.
// 8 waves; wave ti owns rows [ti*64, ti*64+64). Tiles pipelined over 15
// anti-diagonal stages of the 8x8 tile grid.
// ROUND 6 = ROUND 2 (known-good, absmax 0.0) + inner-loop unroll +
// outer stage loop pinned rolled (one I$-resident body). No semantic change.
__global__ __launch_bounds__(512, 1) void dtw_fused(const float* __restrict__ x,
                                                    const float* __restrict__ y,
                                                    float* __restrict__ out)
{
    __shared__ float Dt[8][4096];      // per-wave 64x64 f32 D-tile, XOR-swizzled
    __shared__ float y2s[512];         // per-batch y row sumsq
    __shared__ float rowA[3][8][65];   // [parity][tj][0]=corner, [1+j]=bottom row

    const int b   = blockIdx.x;
    const int tid = threadIdx.x;
    const int w   = tid >> 6;          // wave id == tile row ti
    const int l   = tid & 63;

    const float* xb = x + (size_t)b * 512 * 64;
    const float* yb = y + (size_t)b * 512 * 64;

    // ---------- prologue: y2 (one row per thread) ----------
    {
        const float4* yr = reinterpret_cast<const float4*>(yb + (size_t)tid * 64);
        float s = 0.f;
        #pragma unroll
        for (int q = 0; q < 16; ++q) {
            float4 v = yr[q];
            s += v.x*v.x + v.y*v.y + v.z*v.z + v.w*v.w;
        }
        y2s[tid] = s;
    }
    // rowA init: BIG everywhere except corner for tile (0,0): rowA[2][0][0]=0
    for (int i = tid; i < 3*8*65; i += 512) {
        ((float*)rowA)[i] = (i == 2*8*65) ? 0.0f : BIG;
    }

    // ---------- prologue: A fragments (bf16) + x2 ----------
    const int lr = l & 15;             // row-in-subtile (A) / col-in-subtile (B,C)
    const int lg = l >> 4;             // k-group / C row-group
    short8 afr[4][2];
    float  x2c[4][4];                  // x2 at C-layout rows: mi*16 + lg*4 + i
    {
        float x2f[4];
        #pragma unroll
        for (int mi = 0; mi < 4; ++mi) {
            float part = 0.f;
            #pragma unroll
            for (int ks = 0; ks < 2; ++ks) {
                const float* rp = xb + (size_t)(w*64 + mi*16 + lr) * 64 + ks*32 + lg*8;
                float4 a0 = *reinterpret_cast<const float4*>(rp);
                float4 a1 = *reinterpret_cast<const float4*>(rp + 4);
                afr[mi][ks] = make_frag(a0, a1);
                part += a0.x*a0.x + a0.y*a0.y + a0.z*a0.z + a0.w*a0.w
                      + a1.x*a1.x + a1.y*a1.y + a1.z*a1.z + a1.w*a1.w;
            }
            part += __shfl_xor(part, 16);
            part += __shfl_xor(part, 32);
            x2f[mi] = part;            // sumsq of row mi*16 + (l&15), all 4 groups
        }
        #pragma unroll
        for (int mi = 0; mi < 4; ++mi)
            #pragma unroll
            for (int i = 0; i < 4; ++i)
                x2c[mi][i] = __shfl(x2f[mi], lg*4 + i);
    }

    float* Dw = Dt[w];
    const int xr4 = (l & 7) << 2;      // float-index XOR swizzle for row l
    float colreg = BIG;                // R[w*64+l][tj*64-1] carried across tiles

    #pragma unroll 1
    for (int s = 0; s < 15; ++s) {
        __syncthreads();
        const int tj = s - w;
        if (tj < 0 || tj > 7) continue;
        const int j0 = tj * 64;

        // ---------- GEMM: D-tile via MFMA ----------
        f32x4 acc[4][4] = {};
        #pragma unroll
        for (int ni = 0; ni < 4; ++ni) {
            const float* rp = yb + (size_t)(j0 + ni*16 + lr) * 64 + lg*8;
            float4 b0 = *reinterpret_cast<const float4*>(rp);
            float4 b1 = *reinterpret_cast<const float4*>(rp + 4);
            float4 b2 = *reinterpret_cast<const float4*>(rp + 32);
            float4 b3 = *reinterpret_cast<const float4*>(rp + 36);
            short8 bf0 = make_frag(b0, b1);
            short8 bf1 = make_frag(b2, b3);
            #pragma unroll
            for (int mi = 0; mi < 4; ++mi) {
                acc[mi][ni] = __builtin_amdgcn_mfma_f32_16x16x32_bf16(afr[mi][0], bf0, acc[mi][ni], 0, 0, 0);
                acc[mi][ni] = __builtin_amdgcn_mfma_f32_16x16x32_bf16(afr[mi][1], bf1, acc[mi][ni], 0, 0, 0);
            }
        }
        // epilogue: D = x2 + y2 - 2xy -> swizzled LDS tile (2-way banks: free)
        #pragma unroll
        for (int ni = 0; ni < 4; ++ni) {
            float y2v = y2s[j0 + ni*16 + lr];
            #pragma unroll
            for (int mi = 0; mi < 4; ++mi) {
                #pragma unroll
                for (int i = 0; i < 4; ++i) {
                    int row = mi*16 + lg*4 + i;
                    int col = ni*16 + lr;
                    Dw[(row*64 + col) ^ ((row & 7) << 2)] = x2c[mi][i] + y2v - 2.0f * acc[mi][ni][i];
                }
            }
        }

        // ---------- DTW over the tile: 127 anti-diagonals, 1 cell/lane ----------
        // (verbatim round-2 loop, now unrolled so independent LDS reads hoist)
        const float* rowR = rowA[(s + 2) % 3][tj];   // parity (s-1)%3
        float*       rowW = rowA[s % 3][tj];

        if (tj == 0 && l == 0) rowW[0] = BIG;        // corner for consumer (w+1,0)

        float r1 = colreg;     // R[row][c-1] once active; colreg until then
        float r2 = BIG;
        float saved = rowR[0]; // up-row[j-1]; starts at corner
        float colnext = BIG;

        #pragma unroll
        for (int kk = 0; kk < 127; ++kk) {
            int   c    = kk - l;
            float rowv = rowR[1 + (kk & 63)];
            float dv   = Dw[(l << 6) + (((c & 63)) ^ xr4)];
            float up   = __shfl_up(r1, 1);
            float dg   = __shfl_up(r2, 1);
            float pu   = (l == 0) ? rowv  : up;   // R[row-1][c]
            float pd   = (l == 0) ? saved : dg;   // R[row-1][c-1]
            float nv   = dv + fminf(fminf(pd, pu), r1);
            bool  act  = ((unsigned)c) < 64u;
            r2 = act ? r1 : r2;
            r1 = act ? nv : r1;
            if (c == 63) colnext = nv;                       // tile right column
            if (l == 63 && kk >= 63) rowW[kk - 62] = nv;     // bottom row
            saved = rowv;
        }
        colreg = colnext;
        if (l == 63 && tj < 7) rowA[(s + 1) % 3][tj + 1][0] = colnext;  // corner
    }

    if (w == 7 && l == 63) out[b] = colreg;   // R[511][511]
}

extern "C" void kernel_launch(void* const* d_in, const int* in_sizes, int n_in,
                              void* d_out, int out_size, void* d_ws, size_t ws_size,
                              hipStream_t stream) {
    (void)in_sizes; (void)n_in; (void)d_ws; (void)ws_size; (void)out_size;
    const float* x = (const float*)d_in[0];
    const float* y = (const float*)d_in[1];
    float* out = (float*)d_out;
    dtw_fused<<<128, 512, 0, stream>>>(x, y, out);
}

// Round 7
// 241.839 us; speedup vs baseline: 1.3985x; 1.3985x over previous
//
#include <hip/hip_runtime.h>
#include <hip/hip_bf16.h>

#define BIG 1e30f

typedef __attribute__((ext_vector_type(8))) short short8;
typedef __attribute__((ext_vector_type(4))) float f32x4;

__device__ __forceinline__ unsigned pk_bf16(float lo, float hi) {
    unsigned r;
    asm("v_cvt_pk_bf16_f32 %0, %1, %2" : "=v"(r) : "v"(lo), "v"(hi));
    return r;
}

// 8 consecutive-k f32 values -> one bf16x8 MFMA fragment (k-major)
__device__ __forceinline__ short8 make_frag(float4 a, float4 c) {
    union { unsigned u[4]; short8 s; } cv;
    cv.u[0] = pk_bf16(a.x, a.y);
    cv.u[1] = pk_bf16(a.z, a.w);
    cv.u[2] = pk_bf16(c.x, c.y);
    cv.u[3] = pk_bf16(c.z, c.w);
    return cv.s;
}

// shfl_up(v,1) via DPP wave_shr:1 (VALU pipe, no LDS). Lane 0 keeps old=v,
// matching __shfl_up(v,1) semantics; lane-0 consumers are overridden anyway.
__device__ __forceinline__ float dpp_shr1(float v) {
    int o = __builtin_amdgcn_update_dpp(__float_as_int(v), __float_as_int(v),
                                        0x138, 0xf, 0xf, false);
    return __int_as_float(o);
}

// Fused pairwise-sqeuclidean (bf16 MFMA) + DTW, one block per batch.
// 8 waves; wave ti owns rows [ti*64, ti*64+64). Tiles pipelined over 15
// anti-diagonal stages of the 8x8 tile grid.
// ROUND 7 = ROUND 2 (known-good, absmax 0.0, 249 us) with the two chain
// shuffles moved from ds_bpermute to DPP wave_shr:1. No other change.
__global__ __launch_bounds__(512, 1) void dtw_fused(const float* __restrict__ x,
                                                    const float* __restrict__ y,
                                                    float* __restrict__ out)
{
    __shared__ float Dt[8][4096];      // per-wave 64x64 f32 D-tile, XOR-swizzled
    __shared__ float y2s[512];         // per-batch y row sumsq
    __shared__ float rowA[3][8][65];   // [parity][tj][0]=corner, [1+j]=bottom row

    const int b   = blockIdx.x;
    const int tid = threadIdx.x;
    const int w   = tid >> 6;          // wave id == tile row ti
    const int l   = tid & 63;

    const float* xb = x + (size_t)b * 512 * 64;
    const float* yb = y + (size_t)b * 512 * 64;

    // ---------- prologue: y2 (one row per thread) ----------
    {
        const float4* yr = reinterpret_cast<const float4*>(yb + (size_t)tid * 64);
        float s = 0.f;
        #pragma unroll
        for (int q = 0; q < 16; ++q) {
            float4 v = yr[q];
            s += v.x*v.x + v.y*v.y + v.z*v.z + v.w*v.w;
        }
        y2s[tid] = s;
    }
    // rowA init: BIG everywhere except corner for tile (0,0): rowA[2][0][0]=0
    for (int i = tid; i < 3*8*65; i += 512) {
        ((float*)rowA)[i] = (i == 2*8*65) ? 0.0f : BIG;
    }

    // ---------- prologue: A fragments (bf16) + x2 ----------
    const int lr = l & 15;             // row-in-subtile (A) / col-in-subtile (B,C)
    const int lg = l >> 4;             // k-group / C row-group
    short8 afr[4][2];
    float  x2c[4][4];                  // x2 at C-layout rows: mi*16 + lg*4 + i
    {
        float x2f[4];
        #pragma unroll
        for (int mi = 0; mi < 4; ++mi) {
            float part = 0.f;
            #pragma unroll
            for (int ks = 0; ks < 2; ++ks) {
                const float* rp = xb + (size_t)(w*64 + mi*16 + lr) * 64 + ks*32 + lg*8;
                float4 a0 = *reinterpret_cast<const float4*>(rp);
                float4 a1 = *reinterpret_cast<const float4*>(rp + 4);
                afr[mi][ks] = make_frag(a0, a1);
                part += a0.x*a0.x + a0.y*a0.y + a0.z*a0.z + a0.w*a0.w
                      + a1.x*a1.x + a1.y*a1.y + a1.z*a1.z + a1.w*a1.w;
            }
            part += __shfl_xor(part, 16);
            part += __shfl_xor(part, 32);
            x2f[mi] = part;            // sumsq of row mi*16 + (l&15), all 4 groups
        }
        #pragma unroll
        for (int mi = 0; mi < 4; ++mi)
            #pragma unroll
            for (int i = 0; i < 4; ++i)
                x2c[mi][i] = __shfl(x2f[mi], lg*4 + i);
    }

    float* Dw = Dt[w];
    const int xr4 = (l & 7) << 2;      // float-index XOR swizzle for row l
    float colreg = BIG;                // R[w*64+l][tj*64-1] carried across tiles

    #pragma unroll 1
    for (int s = 0; s < 15; ++s) {
        __syncthreads();
        const int tj = s - w;
        if (tj < 0 || tj > 7) continue;
        const int j0 = tj * 64;

        // ---------- GEMM: D-tile via MFMA ----------
        f32x4 acc[4][4] = {};
        #pragma unroll
        for (int ni = 0; ni < 4; ++ni) {
            const float* rp = yb + (size_t)(j0 + ni*16 + lr) * 64 + lg*8;
            float4 b0 = *reinterpret_cast<const float4*>(rp);
            float4 b1 = *reinterpret_cast<const float4*>(rp + 4);
            float4 b2 = *reinterpret_cast<const float4*>(rp + 32);
            float4 b3 = *reinterpret_cast<const float4*>(rp + 36);
            short8 bf0 = make_frag(b0, b1);
            short8 bf1 = make_frag(b2, b3);
            #pragma unroll
            for (int mi = 0; mi < 4; ++mi) {
                acc[mi][ni] = __builtin_amdgcn_mfma_f32_16x16x32_bf16(afr[mi][0], bf0, acc[mi][ni], 0, 0, 0);
                acc[mi][ni] = __builtin_amdgcn_mfma_f32_16x16x32_bf16(afr[mi][1], bf1, acc[mi][ni], 0, 0, 0);
            }
        }
        // epilogue: D = x2 + y2 - 2xy -> swizzled LDS tile (2-way banks: free)
        #pragma unroll
        for (int ni = 0; ni < 4; ++ni) {
            float y2v = y2s[j0 + ni*16 + lr];
            #pragma unroll
            for (int mi = 0; mi < 4; ++mi) {
                #pragma unroll
                for (int i = 0; i < 4; ++i) {
                    int row = mi*16 + lg*4 + i;
                    int col = ni*16 + lr;
                    Dw[(row*64 + col) ^ ((row & 7) << 2)] = x2c[mi][i] + y2v - 2.0f * acc[mi][ni][i];
                }
            }
        }

        // ---------- DTW over the tile: 127 anti-diagonals, 1 cell/lane ----------
        // (verbatim round-2 loop; shuffles now DPP wave_shr:1 on the VALU pipe)
        const float* rowR = rowA[(s + 2) % 3][tj];   // parity (s-1)%3
        float*       rowW = rowA[s % 3][tj];

        if (tj == 0 && l == 0) rowW[0] = BIG;        // corner for consumer (w+1,0)

        float r1 = colreg;     // R[row][c-1] once active; colreg until then
        float r2 = BIG;
        float saved = rowR[0]; // up-row[j-1]; starts at corner
        float colnext = BIG;

        for (int kk = 0; kk < 127; ++kk) {
            int   c    = kk - l;
            float rowv = rowR[1 + (kk & 63)];
            float dv   = Dw[(l << 6) + (((c & 63)) ^ xr4)];
            float up   = dpp_shr1(r1);
            float dg   = dpp_shr1(r2);
            float pu   = (l == 0) ? rowv  : up;   // R[row-1][c]
            float pd   = (l == 0) ? saved : dg;   // R[row-1][c-1]
            float nv   = dv + fminf(fminf(pd, pu), r1);
            bool  act  = ((unsigned)c) < 64u;
            r2 = act ? r1 : r2;
            r1 = act ? nv : r1;
            if (c == 63) colnext = nv;                       // tile right column
            if (l == 63 && kk >= 63) rowW[kk - 62] = nv;     // bottom row
            saved = rowv;
        }
        colreg = colnext;
        if (l == 63 && tj < 7) rowA[(s + 1) % 3][tj + 1][0] = colnext;  // corner
    }

    if (w == 7 && l == 63) out[b] = colreg;   // R[511][511]
}

extern "C" void kernel_launch(void* const* d_in, const int* in_sizes, int n_in,
                              void* d_out, int out_size, void* d_ws, size_t ws_size,
                              hipStream_t stream) {
    (void)in_sizes; (void)n_in; (void)d_ws; (void)ws_size; (void)out_size;
    const float* x = (const float*)d_in[0];
    const float* y = (const float*)d_in[1];
    float* out = (float*)d_out;
    dtw_fused<<<128, 512, 0, stream>>>(x, y, out);
}

// Round 8
// 190.908 us; speedup vs baseline: 1.7716x; 1.2668x over previous
//
#include <hip/hip_runtime.h>
#include <hip/hip_bf16.h>

#define BIG 1e30f

typedef __attribute__((ext_vector_type(8))) short short8;
typedef __attribute__((ext_vector_type(4))) float f32x4;

__device__ __forceinline__ unsigned pk_bf16(float lo, float hi) {
    unsigned r;
    asm("v_cvt_pk_bf16_f32 %0, %1, %2" : "=v"(r) : "v"(lo), "v"(hi));
    return r;
}

// 8 consecutive-k f32 values -> one bf16x8 MFMA fragment (k-major)
__device__ __forceinline__ short8 make_frag(float4 a, float4 c) {
    union { unsigned u[4]; short8 s; } cv;
    cv.u[0] = pk_bf16(a.x, a.y);
    cv.u[1] = pk_bf16(a.z, a.w);
    cv.u[2] = pk_bf16(c.x, c.y);
    cv.u[3] = pk_bf16(c.z, c.w);
    return cv.s;
}

// shfl_up(v,1) via DPP wave_shr:1 (VALU pipe; validated round 7, absmax 0.0).
__device__ __forceinline__ float dpp_shr1(float v) {
    int o = __builtin_amdgcn_update_dpp(__float_as_int(v), __float_as_int(v),
                                        0x138, 0xf, 0xf, false);
    return __int_as_float(o);
}

// Fused pairwise-sqeuclidean (bf16 MFMA) + DTW, one block per batch.
// 8 waves; wave ti owns rows [ti*64, ti*64+64). Tiles pipelined over 15
// anti-diagonal stages of the 8x8 tile grid.
// ROUND 8 = ROUND 7 (verified step semantics, DPP chain) with the DTW loop
// split into 8 chunks of 16 steps: per chunk, batch-prefetch 16 dv + 16 rowv
// into registers (one LDS latency fill), then 16 pure-VALU steps. Step
// semantics verbatim; kk runs to 127 (no-op step) with the rowW store
// guarded kk<127 (unguarded it aliases rowA[s%3][tj+1][0] = next corner).
__global__ __launch_bounds__(512, 1) void dtw_fused(const float* __restrict__ x,
                                                    const float* __restrict__ y,
                                                    float* __restrict__ out)
{
    __shared__ float Dt[8][4096];      // per-wave 64x64 f32 D-tile, XOR-swizzled
    __shared__ float y2s[512];         // per-batch y row sumsq
    __shared__ float rowA[3][8][65];   // [parity][tj][0]=corner, [1+j]=bottom row

    const int b   = blockIdx.x;
    const int tid = threadIdx.x;
    const int w   = tid >> 6;          // wave id == tile row ti
    const int l   = tid & 63;

    const float* xb = x + (size_t)b * 512 * 64;
    const float* yb = y + (size_t)b * 512 * 64;

    // ---------- prologue: y2 (one row per thread) ----------
    {
        const float4* yr = reinterpret_cast<const float4*>(yb + (size_t)tid * 64);
        float s = 0.f;
        #pragma unroll
        for (int q = 0; q < 16; ++q) {
            float4 v = yr[q];
            s += v.x*v.x + v.y*v.y + v.z*v.z + v.w*v.w;
        }
        y2s[tid] = s;
    }
    // rowA init: BIG everywhere except corner for tile (0,0): rowA[2][0][0]=0
    for (int i = tid; i < 3*8*65; i += 512) {
        ((float*)rowA)[i] = (i == 2*8*65) ? 0.0f : BIG;
    }

    // ---------- prologue: A fragments (bf16) + x2 ----------
    const int lr = l & 15;             // row-in-subtile (A) / col-in-subtile (B,C)
    const int lg = l >> 4;             // k-group / C row-group
    short8 afr[4][2];
    float  x2c[4][4];                  // x2 at C-layout rows: mi*16 + lg*4 + i
    {
        float x2f[4];
        #pragma unroll
        for (int mi = 0; mi < 4; ++mi) {
            float part = 0.f;
            #pragma unroll
            for (int ks = 0; ks < 2; ++ks) {
                const float* rp = xb + (size_t)(w*64 + mi*16 + lr) * 64 + ks*32 + lg*8;
                float4 a0 = *reinterpret_cast<const float4*>(rp);
                float4 a1 = *reinterpret_cast<const float4*>(rp + 4);
                afr[mi][ks] = make_frag(a0, a1);
                part += a0.x*a0.x + a0.y*a0.y + a0.z*a0.z + a0.w*a0.w
                      + a1.x*a1.x + a1.y*a1.y + a1.z*a1.z + a1.w*a1.w;
            }
            part += __shfl_xor(part, 16);
            part += __shfl_xor(part, 32);
            x2f[mi] = part;            // sumsq of row mi*16 + (l&15), all 4 groups
        }
        #pragma unroll
        for (int mi = 0; mi < 4; ++mi)
            #pragma unroll
            for (int i = 0; i < 4; ++i)
                x2c[mi][i] = __shfl(x2f[mi], lg*4 + i);
    }

    float* Dw = Dt[w];
    const int xr4 = (l & 7) << 2;      // float-index XOR swizzle for row l
    float colreg = BIG;                // R[w*64+l][tj*64-1] carried across tiles

    #pragma unroll 1
    for (int s = 0; s < 15; ++s) {
        __syncthreads();
        const int tj = s - w;
        if (tj < 0 || tj > 7) continue;
        const int j0 = tj * 64;

        // ---------- GEMM: D-tile via MFMA ----------
        f32x4 acc[4][4] = {};
        #pragma unroll
        for (int ni = 0; ni < 4; ++ni) {
            const float* rp = yb + (size_t)(j0 + ni*16 + lr) * 64 + lg*8;
            float4 b0 = *reinterpret_cast<const float4*>(rp);
            float4 b1 = *reinterpret_cast<const float4*>(rp + 4);
            float4 b2 = *reinterpret_cast<const float4*>(rp + 32);
            float4 b3 = *reinterpret_cast<const float4*>(rp + 36);
            short8 bf0 = make_frag(b0, b1);
            short8 bf1 = make_frag(b2, b3);
            #pragma unroll
            for (int mi = 0; mi < 4; ++mi) {
                acc[mi][ni] = __builtin_amdgcn_mfma_f32_16x16x32_bf16(afr[mi][0], bf0, acc[mi][ni], 0, 0, 0);
                acc[mi][ni] = __builtin_amdgcn_mfma_f32_16x16x32_bf16(afr[mi][1], bf1, acc[mi][ni], 0, 0, 0);
            }
        }
        // epilogue: D = x2 + y2 - 2xy -> swizzled LDS tile (2-way banks: free)
        #pragma unroll
        for (int ni = 0; ni < 4; ++ni) {
            float y2v = y2s[j0 + ni*16 + lr];
            #pragma unroll
            for (int mi = 0; mi < 4; ++mi) {
                #pragma unroll
                for (int i = 0; i < 4; ++i) {
                    int row = mi*16 + lg*4 + i;
                    int col = ni*16 + lr;
                    Dw[(row*64 + col) ^ ((row & 7) << 2)] = x2c[mi][i] + y2v - 2.0f * acc[mi][ni][i];
                }
            }
        }

        // ---------- DTW over the tile: 128 steps in 8 chunks of 16 ----------
        const float* rowR = rowA[(s + 2) % 3][tj];   // parity (s-1)%3
        float*       rowW = rowA[s % 3][tj];

        if (tj == 0 && l == 0) rowW[0] = BIG;        // corner for consumer (w+1,0)

        float r1 = colreg;     // R[row][c-1] once active; colreg until then
        float r2 = BIG;
        float saved = rowR[0]; // up-row[j-1]; starts at corner
        float colnext = BIG;

        #pragma unroll 1
        for (int k0 = 0; k0 < 128; k0 += 16) {
            // prefetch: one batched LDS fill per chunk
            float dvb[16], rvb[16];
            #pragma unroll
            for (int u = 0; u < 16; ++u) {
                int kk = k0 + u;
                rvb[u] = rowR[1 + (kk & 63)];
                dvb[u] = Dw[(l << 6) + (((kk - l) & 63) ^ xr4)];
            }
            // compute: 16 steps, register/DPP only (verbatim round-2 semantics)
            #pragma unroll
            for (int u = 0; u < 16; ++u) {
                int   kk   = k0 + u;
                int   c    = kk - l;
                float rowv = rvb[u];
                float dv   = dvb[u];
                float up   = dpp_shr1(r1);
                float dg   = dpp_shr1(r2);
                float pu   = (l == 0) ? rowv  : up;   // R[row-1][c]
                float pd   = (l == 0) ? saved : dg;   // R[row-1][c-1]
                float nv   = dv + fminf(fminf(pd, pu), r1);
                bool  act  = ((unsigned)c) < 64u;
                r2 = act ? r1 : r2;
                r1 = act ? nv : r1;
                if (c == 63) colnext = nv;                       // right column
                if (l == 63 && kk >= 63 && kk < 127) rowW[kk - 62] = nv;
                saved = rowv;
            }
        }
        colreg = colnext;
        if (l == 63 && tj < 7) rowA[(s + 1) % 3][tj + 1][0] = colnext;  // corner
    }

    if (w == 7 && l == 63) out[b] = colreg;   // R[511][511]
}

extern "C" void kernel_launch(void* const* d_in, const int* in_sizes, int n_in,
                              void* d_out, int out_size, void* d_ws, size_t ws_size,
                              hipStream_t stream) {
    (void)in_sizes; (void)n_in; (void)d_ws; (void)ws_size; (void)out_size;
    const float* x = (const float*)d_in[0];
    const float* y = (const float*)d_in[1];
    float* out = (float*)d_out;
    dtw_fused<<<128, 512, 0, stream>>>(x, y, out);
}

// Round 9
// 183.431 us; speedup vs baseline: 1.8438x; 1.0408x over previous
//
#include <hip/hip_runtime.h>
#include <hip/hip_bf16.h>

#define BIG 1e30f

typedef __attribute__((ext_vector_type(8))) short short8;
typedef __attribute__((ext_vector_type(4))) float f32x4;

// Forces the preceding ds_read batch to complete HERE and stops the scheduler
// from moving register-only compute above the wait (guide rule #18).
#define LGKM_FENCE() do { asm volatile("s_waitcnt lgkmcnt(0)" ::: "memory"); \
                          __builtin_amdgcn_sched_barrier(0); } while (0)
#define SCHED_FENCE() __builtin_amdgcn_sched_barrier(0)

__device__ __forceinline__ unsigned pk_bf16(float lo, float hi) {
    unsigned r;
    asm("v_cvt_pk_bf16_f32 %0, %1, %2" : "=v"(r) : "v"(lo), "v"(hi));
    return r;
}

// 8 consecutive-k f32 values -> one bf16x8 MFMA fragment (k-major)
__device__ __forceinline__ short8 make_frag(float4 a, float4 c) {
    union { unsigned u[4]; short8 s; } cv;
    cv.u[0] = pk_bf16(a.x, a.y);
    cv.u[1] = pk_bf16(a.z, a.w);
    cv.u[2] = pk_bf16(c.x, c.y);
    cv.u[3] = pk_bf16(c.z, c.w);
    return cv.s;
}

// shfl_up(v,1) via DPP wave_shr:1 (VALU pipe; validated round 7, absmax 0.0).
__device__ __forceinline__ float dpp_shr1(float v) {
    int o = __builtin_amdgcn_update_dpp(__float_as_int(v), __float_as_int(v),
                                        0x138, 0xf, 0xf, false);
    return __int_as_float(o);
}

// Fused pairwise-sqeuclidean (bf16 MFMA) + DTW, one block per batch.
// 8 waves; wave ti owns rows [ti*64, ti*64+64). Tiles pipelined over 15
// anti-diagonal stages of the 8x8 tile grid.
// ROUND 9 = ROUND 8 step semantics verbatim, with the DTW chunk pipeline
// pinned explicitly: ping-pong A/B register buffers (static names, no
// runtime indexing), sched_barrier-pinned load issue, lgkmcnt(0) fences,
// and the per-step conditional rowW ds_write hoisted to one masked store
// block per 16-step chunk (register-buffered nv history).
__global__ __launch_bounds__(512, 1) void dtw_fused(const float* __restrict__ x,
                                                    const float* __restrict__ y,
                                                    float* __restrict__ out)
{
    __shared__ float Dt[8][4096];      // per-wave 64x64 f32 D-tile, XOR-swizzled
    __shared__ float y2s[512];         // per-batch y row sumsq
    __shared__ float rowA[3][8][65];   // [parity][tj][0]=corner, [1+j]=bottom row

    const int b   = blockIdx.x;
    const int tid = threadIdx.x;
    const int w   = tid >> 6;          // wave id == tile row ti
    const int l   = tid & 63;

    const float* xb = x + (size_t)b * 512 * 64;
    const float* yb = y + (size_t)b * 512 * 64;

    // ---------- prologue: y2 (one row per thread) ----------
    {
        const float4* yr = reinterpret_cast<const float4*>(yb + (size_t)tid * 64);
        float s = 0.f;
        #pragma unroll
        for (int q = 0; q < 16; ++q) {
            float4 v = yr[q];
            s += v.x*v.x + v.y*v.y + v.z*v.z + v.w*v.w;
        }
        y2s[tid] = s;
    }
    // rowA init: BIG everywhere except corner for tile (0,0): rowA[2][0][0]=0
    for (int i = tid; i < 3*8*65; i += 512) {
        ((float*)rowA)[i] = (i == 2*8*65) ? 0.0f : BIG;
    }

    // ---------- prologue: A fragments (bf16) + x2 ----------
    const int lr = l & 15;             // row-in-subtile (A) / col-in-subtile (B,C)
    const int lg = l >> 4;             // k-group / C row-group
    short8 afr[4][2];
    float  x2c[4][4];                  // x2 at C-layout rows: mi*16 + lg*4 + i
    {
        float x2f[4];
        #pragma unroll
        for (int mi = 0; mi < 4; ++mi) {
            float part = 0.f;
            #pragma unroll
            for (int ks = 0; ks < 2; ++ks) {
                const float* rp = xb + (size_t)(w*64 + mi*16 + lr) * 64 + ks*32 + lg*8;
                float4 a0 = *reinterpret_cast<const float4*>(rp);
                float4 a1 = *reinterpret_cast<const float4*>(rp + 4);
                afr[mi][ks] = make_frag(a0, a1);
                part += a0.x*a0.x + a0.y*a0.y + a0.z*a0.z + a0.w*a0.w
                      + a1.x*a1.x + a1.y*a1.y + a1.z*a1.z + a1.w*a1.w;
            }
            part += __shfl_xor(part, 16);
            part += __shfl_xor(part, 32);
            x2f[mi] = part;            // sumsq of row mi*16 + (l&15), all 4 groups
        }
        #pragma unroll
        for (int mi = 0; mi < 4; ++mi)
            #pragma unroll
            for (int i = 0; i < 4; ++i)
                x2c[mi][i] = __shfl(x2f[mi], lg*4 + i);
    }

    float* Dw = Dt[w];
    const int xr4 = (l & 7) << 2;      // float-index XOR swizzle for row l
    float colreg = BIG;                // R[w*64+l][tj*64-1] carried across tiles

    #pragma unroll 1
    for (int s = 0; s < 15; ++s) {
        __syncthreads();
        const int tj = s - w;
        if (tj < 0 || tj > 7) continue;
        const int j0 = tj * 64;

        // ---------- GEMM: D-tile via MFMA ----------
        f32x4 acc[4][4] = {};
        #pragma unroll
        for (int ni = 0; ni < 4; ++ni) {
            const float* rp = yb + (size_t)(j0 + ni*16 + lr) * 64 + lg*8;
            float4 b0 = *reinterpret_cast<const float4*>(rp);
            float4 b1 = *reinterpret_cast<const float4*>(rp + 4);
            float4 b2 = *reinterpret_cast<const float4*>(rp + 32);
            float4 b3 = *reinterpret_cast<const float4*>(rp + 36);
            short8 bf0 = make_frag(b0, b1);
            short8 bf1 = make_frag(b2, b3);
            #pragma unroll
            for (int mi = 0; mi < 4; ++mi) {
                acc[mi][ni] = __builtin_amdgcn_mfma_f32_16x16x32_bf16(afr[mi][0], bf0, acc[mi][ni], 0, 0, 0);
                acc[mi][ni] = __builtin_amdgcn_mfma_f32_16x16x32_bf16(afr[mi][1], bf1, acc[mi][ni], 0, 0, 0);
            }
        }
        // epilogue: D = x2 + y2 - 2xy -> swizzled LDS tile (2-way banks: free)
        #pragma unroll
        for (int ni = 0; ni < 4; ++ni) {
            float y2v = y2s[j0 + ni*16 + lr];
            #pragma unroll
            for (int mi = 0; mi < 4; ++mi) {
                #pragma unroll
                for (int i = 0; i < 4; ++i) {
                    int row = mi*16 + lg*4 + i;
                    int col = ni*16 + lr;
                    Dw[(row*64 + col) ^ ((row & 7) << 2)] = x2c[mi][i] + y2v - 2.0f * acc[mi][ni][i];
                }
            }
        }

        // ---------- DTW over the tile: 128 steps, fence-pinned chunks ----------
        const float* rowR = rowA[(s + 2) % 3][tj];   // parity (s-1)%3
        float*       rowW = rowA[s % 3][tj];

        if (tj == 0 && l == 0) rowW[0] = BIG;        // corner for consumer (w+1,0)

        float r1 = colreg;     // R[row][c-1] once active; colreg until then
        float r2 = BIG;
        float saved = rowR[0]; // up-row[j-1]; starts at corner
        float colnext = BIG;

        auto issue_loads = [&](float (&dvb)[16], float (&rvb)[16], int k0) {
            #pragma unroll
            for (int u = 0; u < 16; ++u) {
                int kk = k0 + u;
                rvb[u] = rowR[1 + (kk & 63)];
                dvb[u] = Dw[(l << 6) + (((kk - l) & 63) ^ xr4)];
            }
        };
        auto compute16 = [&](float (&dvb)[16], float (&rvb)[16], int k0) {
            float rw[16];
            #pragma unroll
            for (int u = 0; u < 16; ++u) {
                int   kk   = k0 + u;
                int   c    = kk - l;
                float rowv = rvb[u];
                float dv   = dvb[u];
                float up   = dpp_shr1(r1);
                float dg   = dpp_shr1(r2);
                float pu   = (l == 0) ? rowv  : up;   // R[row-1][c]
                float pd   = (l == 0) ? saved : dg;   // R[row-1][c-1]
                float nv   = dv + fminf(fminf(pd, pu), r1);
                bool  act  = ((unsigned)c) < 64u;
                r2 = act ? r1 : r2;
                r1 = act ? nv : r1;
                colnext = (c == 63) ? nv : colnext;    // tile right column
                rw[u] = nv;                            // buffered bottom-row value
                saved = rowv;
            }
            if (l == 63) {                             // one store block per chunk
                #pragma unroll
                for (int u = 0; u < 16; ++u) {
                    int kk = k0 + u;
                    if ((unsigned)(kk - 63) < 64u) rowW[kk - 62] = rw[u];
                }
            }
        };

        float dvbA[16], rvbA[16], dvbB[16], rvbB[16];
        issue_loads(dvbA, rvbA, 0);
        LGKM_FENCE();
        #pragma unroll 1
        for (int k0 = 0; k0 < 128; k0 += 32) {
            issue_loads(dvbB, rvbB, k0 + 16);   // next chunk in flight
            SCHED_FENCE();
            compute16(dvbA, rvbA, k0);          // pure VALU/DPP on chunk A
            LGKM_FENCE();                       // B complete
            if (k0 < 96) issue_loads(dvbA, rvbA, k0 + 32);
            SCHED_FENCE();
            compute16(dvbB, rvbB, k0 + 16);
            LGKM_FENCE();                       // A complete
        }
        colreg = colnext;
        if (l == 63 && tj < 7) rowA[(s + 1) % 3][tj + 1][0] = colnext;  // corner
    }

    if (w == 7 && l == 63) out[b] = colreg;   // R[511][511]
}

extern "C" void kernel_launch(void* const* d_in, const int* in_sizes, int n_in,
                              void* d_out, int out_size, void* d_ws, size_t ws_size,
                              hipStream_t stream) {
    (void)in_sizes; (void)n_in; (void)d_ws; (void)ws_size; (void)out_size;
    const float* x = (const float*)d_in[0];
    const float* y = (const float*)d_in[1];
    float* out = (float*)d_out;
    dtw_fused<<<128, 512, 0, stream>>>(x, y, out);
}